// Round 4
// baseline (1670.621 us; speedup 1.0000x reference)
//
#include <hip/hip_runtime.h>
#include <hip/hip_bf16.h>
#include <float.h>
#include <cstdint>

// ---------------------------------------------------------------------------
// RCSLS: out = ( topk10sum(X_trans@Z_tgt^T)/10 + topk10sum(Y_tgt@Z_trans^T)/10
//               - 2*sum(X_trans*Y_tgt) ) / 4096
// B=4096, N=32768, d=512, k=10.  Inputs f32; GEMMs in bf16 MFMA.
// Top-k carried as sortable-u16 (monotone bf16 map) for packed 16-bit sorts.
// Per (row, 64-col half) we keep top-4 (superset argument: P(>=5 of row top-10
// in one 64-col window) ~ 7e-12 per window — exact in practice).
// ---------------------------------------------------------------------------

#define B_ROWS 4096
#define N_COLS 32768
#define D_K    512
#define BM     128
#define BN     128
#define BKT    64
#define NCHUNK (N_COLS / BN)   // 256
#define CSTRIDE 134            // u16 C-dump stride: dump AND scan conflict-free

typedef __bf16 bf16x8 __attribute__((ext_vector_type(8)));
typedef float  f32x4  __attribute__((ext_vector_type(4)));
typedef unsigned short u16x2 __attribute__((ext_vector_type(2)));

__device__ __forceinline__ unsigned short f2bf(float f) {
    unsigned int u = __float_as_uint(f);
    u += 0x7FFFu + ((u >> 16) & 1u);   // RNE
    return (unsigned short)(u >> 16);
}
// monotone map: f32 order == unsigned order of f2sort(f)
__device__ __forceinline__ unsigned short f2sort(float f) {
    unsigned int x = f2bf(f);
    return (unsigned short)(x ^ (0x8000u | ((x >> 15) * 0x7FFFu)));
}
__device__ __forceinline__ float sort2f(unsigned int y) {
    unsigned int x = (y & 0x8000u) ? (y ^ 0x8000u) : (~y & 0xFFFFu);
    return __uint_as_float(x << 16);
}

// ---- zero the 3 scalar accumulators -----------------------------------------
__global__ void zero_scalars(float* sc) {
    if (threadIdx.x < 3) sc[threadIdx.x] = 0.0f;
}

// ---- fused f32->bf16 conversion (4 arrays) + dot(X,Y); grid.y selects ------
__global__ void prep_kernel(const float4* __restrict__ X,
                            const float4* __restrict__ Y,
                            const float4* __restrict__ Zt,
                            const float4* __restrict__ Ztr,
                            ushort4* __restrict__ A0, ushort4* __restrict__ A1,
                            ushort4* __restrict__ B0, ushort4* __restrict__ B1,
                            float* __restrict__ dotacc) {
    const int z = blockIdx.y;
    int i = blockIdx.x * 256 + threadIdx.x;
    const int stride = gridDim.x * 256;
    if (z == 0) {
        float s = 0.0f;
        for (; i < B_ROWS * D_K / 4; i += stride) {
            float4 x = X[i], y = Y[i];
            ushort4 u; u.x = f2bf(x.x); u.y = f2bf(x.y);
            u.z = f2bf(x.z); u.w = f2bf(x.w);
            A0[i] = u;
            s += x.x * y.x + x.y * y.y + x.z * y.z + x.w * y.w;
        }
        for (int o = 32; o > 0; o >>= 1) s += __shfl_down(s, o);
        __shared__ float wsum[4];
        int lane = threadIdx.x & 63, w = threadIdx.x >> 6;
        if (lane == 0) wsum[w] = s;
        __syncthreads();
        if (threadIdx.x == 0)
            atomicAdd(dotacc, wsum[0] + wsum[1] + wsum[2] + wsum[3]);
    } else {
        const float4* src = (z == 1) ? Y : (z == 2) ? Zt : Ztr;
        ushort4* dst = (z == 1) ? A1 : (z == 2) ? B0 : B1;
        int n4 = (z == 1) ? (B_ROWS * D_K / 4) : (N_COLS * D_K / 4);
        for (; i < n4; i += stride) {
            float4 f = src[i];
            ushort4 u; u.x = f2bf(f.x); u.y = f2bf(f.y);
            u.z = f2bf(f.z); u.w = f2bf(f.w);
            dst[i] = u;
        }
    }
}

// ---- bf16 GEMM + per-(row, 64-col-half) top-4 -------------------------------
// grid (8192, 2): y selects which GEMM. x is XCD-swizzled as before.
// Staging: registers (8 x dwordx4 / thread) double-buffer the k-tiles so L2
// latency hides under ds_read+MFMA instead of draining at the barrier.
__global__ __launch_bounds__(256, 3)
void gemm_topk_kernel(const unsigned short* __restrict__ A0g,
                      const unsigned short* __restrict__ A1g,
                      const unsigned short* __restrict__ B0g,
                      const unsigned short* __restrict__ B1g,
                      uint2* __restrict__ P0, uint2* __restrict__ P1) {
    const unsigned short* A  = blockIdx.y ? A1g : A0g;
    const unsigned short* Bm = blockIdx.y ? B1g : B0g;
    uint2* P2 = blockIdx.y ? P1 : P0;

    __shared__ __align__(128) unsigned short smem[BM * CSTRIDE]; // 34304 B
    unsigned short* Alds = smem;             // 16 segs * 512 shorts (16 KB)
    unsigned short* Blds = smem + 16 * 512;  // 16 KB

    const int tid  = threadIdx.x;
    const int lane = tid & 63;
    const int w    = tid >> 6;
    const int wm   = w >> 1;
    const int wn   = w & 1;
    const int quad = lane >> 4;
    const int mrow = lane & 15;

    // XCD swizzle
    const int b      = blockIdx.x;
    const int xcd    = b & 7;
    const int ii     = b >> 3;            // 0..1023
    const int cw     = ii & 15;
    const int rowblk = (ii >> 4) & 31;
    const int cg     = ii >> 9;           // 0..1
    const int bn     = xcd * 32 + cg * 16 + cw;
    const int row0   = rowblk * BM;
    const int col0   = bn * BN;

    // per-lane global pointers (segment s = w*4+c):
    //   row-in-tile = (s>>1)*16 + (lane&15); col = (s&1)*32 + (lane>>4)*8
    const uint4* gA[4];
    const uint4* gB[4];
    #pragma unroll
    for (int c = 0; c < 4; ++c) {
        int s  = w * 4 + c;
        int r  = (s >> 1) * 16 + mrow;
        int kc = (s & 1) * 32 + quad * 8;
        gA[c] = (const uint4*)(A  + (size_t)(row0 + r) * D_K + kc);
        gB[c] = (const uint4*)(Bm + (size_t)(col0 + r) * D_K + kc);
    }

    uint4 ra[4], rb[4];
    #pragma unroll
    for (int c = 0; c < 4; ++c) { ra[c] = gA[c][0]; rb[c] = gB[c][0]; }

    f32x4 acc[4][4];
    #pragma unroll
    for (int mi = 0; mi < 4; ++mi)
        #pragma unroll
        for (int ni = 0; ni < 4; ++ni)
            acc[mi][ni] = (f32x4){0.f, 0.f, 0.f, 0.f};

    for (int kt = 0; kt < D_K / BKT; ++kt) {
        // commit staged regs to LDS (implicit vmcnt wait lands here)
        #pragma unroll
        for (int c = 0; c < 4; ++c) {
            int s = w * 4 + c;
            *(uint4*)(Alds + s * 512 + lane * 8) = ra[c];
            *(uint4*)(Blds + s * 512 + lane * 8) = rb[c];
        }
        __syncthreads();
        // issue next tile's loads now; latency overlaps the compute below
        if (kt < D_K / BKT - 1) {
            #pragma unroll
            for (int c = 0; c < 4; ++c) {
                ra[c] = gA[c][(kt + 1) * 8];
                rb[c] = gB[c][(kt + 1) * 8];
            }
        }
        #pragma unroll
        for (int kk32 = 0; kk32 < 2; ++kk32) {
            bf16x8 af[4], bfr[4];
            #pragma unroll
            for (int mi = 0; mi < 4; ++mi)
                af[mi] = *(const bf16x8*)(Alds + ((wm * 4 + mi) * 2 + kk32) * 512 + lane * 8);
            #pragma unroll
            for (int ni = 0; ni < 4; ++ni)
                bfr[ni] = *(const bf16x8*)(Blds + ((wn * 4 + ni) * 2 + kk32) * 512 + lane * 8);
            #pragma unroll
            for (int mi = 0; mi < 4; ++mi)
                #pragma unroll
                for (int ni = 0; ni < 4; ++ni)
                    acc[mi][ni] = __builtin_amdgcn_mfma_f32_16x16x32_bf16(
                        af[mi], bfr[ni], acc[mi][ni], 0, 0, 0);
        }
        __syncthreads();
    }

    // ---- dump C as sortable u16, stride 134 (conflict-free) ----
    unsigned short* Cs = smem;
    #pragma unroll
    for (int mi = 0; mi < 4; ++mi) {
        int r = wm * 64 + mi * 16 + quad * 4;
        #pragma unroll
        for (int ni = 0; ni < 4; ++ni) {
            int cc = wn * 64 + ni * 16 + mrow;
            #pragma unroll
            for (int reg = 0; reg < 4; ++reg)
                Cs[(r + reg) * CSTRIDE + cc] = f2sort(acc[mi][ni][reg]);
        }
    }
    __syncthreads();

    // ---- per-half-row packed top-4: row = w*32+(lane>>1), half = lane&1 ----
    const int row  = w * 32 + (lane >> 1);
    const int half = lane & 1;
    const u16x2* rp = (const u16x2*)(Cs + row * CSTRIDE + half * 64);
    u16x2 t[4];
    #pragma unroll
    for (int i = 0; i < 4; ++i) t[i] = (u16x2){0, 0};
    #pragma unroll 8
    for (int j = 0; j < 32; ++j) {
        u16x2 v = rp[j];                       // (even col, odd col)
        #pragma unroll
        for (int i = 0; i < 4; ++i) {
            u16x2 hi = __builtin_elementwise_max(t[i], v);
            v = __builtin_elementwise_min(t[i], v);
            t[i] = hi;
        }
    }
    // bitonic first-stage: top-4 multiset of the 64 cols
    unsigned int m0 = max((unsigned int)t[0].x, (unsigned int)t[3].y);
    unsigned int m1 = max((unsigned int)t[1].x, (unsigned int)t[2].y);
    unsigned int m2 = max((unsigned int)t[2].x, (unsigned int)t[1].y);
    unsigned int m3 = max((unsigned int)t[3].x, (unsigned int)t[0].y);
    uint2 outv = make_uint2(m0 | (m1 << 16), m2 | (m3 << 16));
    P2[((size_t)(row0 + row) * NCHUNK + bn) * 2 + half] = outv;
}

// ---- per-row exact top-10 over 2048 u16 candidates; one wave per row --------
// grid (1024, 2): y selects which GEMM's P / accumulator.
__global__ __launch_bounds__(256, 4)
void merge_topk_kernel(const unsigned int* __restrict__ P0,
                       const unsigned int* __restrict__ P1,
                       float* __restrict__ sc) {
    const int g    = blockIdx.y;
    const int lane = threadIdx.x & 63;
    const int w    = threadIdx.x >> 6;
    const int row  = blockIdx.x * 4 + w;
    const unsigned int* Rp = (g ? P1 : P0) + (size_t)row * (NCHUNK * 4); // 1024 u32

    u16x2 t[10];
    #pragma unroll
    for (int i = 0; i < 10; ++i) t[i] = (u16x2){0, 0};
    #pragma unroll 4
    for (int it = 0; it < 16; ++it) {
        unsigned int raw = Rp[lane + 64 * it];
        u16x2 v = *(u16x2*)&raw;
        #pragma unroll
        for (int i = 0; i < 10; ++i) {
            u16x2 hi = __builtin_elementwise_max(t[i], v);
            v = __builtin_elementwise_min(t[i], v);
            t[i] = hi;
        }
    }
    // per-lane top-10 multiset, packed with (lane,slot) for unique extraction
    unsigned int wreg[10];
    #pragma unroll
    for (int i = 0; i < 10; ++i) {
        unsigned int mv = max((unsigned int)t[i].x,
                              (unsigned int)t[9 - i].y);
        wreg[i] = (mv << 16) | ((unsigned int)lane << 4) | (unsigned int)i;
    }
    float sum10 = 0.0f;
    #pragma unroll
    for (int iter = 0; iter < 10; ++iter) {
        unsigned int mx = wreg[0];
        #pragma unroll
        for (int s = 1; s < 10; ++s) mx = max(mx, wreg[s]);
        #pragma unroll
        for (int o = 32; o > 0; o >>= 1)
            mx = max(mx, (unsigned int)__shfl_xor((int)mx, o));
        sum10 += sort2f(mx >> 16);
        #pragma unroll
        for (int s = 0; s < 10; ++s)
            if (wreg[s] == mx) wreg[s] = 0u;
    }
    if (lane == 0) atomicAdd(sc + 1 + g, sum10);
}

// ---- final scalar -----------------------------------------------------------
__global__ void finalize_kernel(const float* __restrict__ sc,
                                float* __restrict__ out) {
    if (threadIdx.x == 0) {
        float f = (sc[1] * 0.1f + sc[2] * 0.1f - 2.0f * sc[0]) * (1.0f / 4096.0f);
        out[0] = f;
    }
}

extern "C" void kernel_launch(void* const* d_in, const int* in_sizes, int n_in,
                              void* d_out, int out_size, void* d_ws, size_t ws_size,
                              hipStream_t stream) {
    const float* X_trans = (const float*)d_in[1];
    const float* Y_tgt   = (const float*)d_in[2];
    const float* Z_trans = (const float*)d_in[4];
    const float* Z_tgt   = (const float*)d_in[5];

    char* ws = (char*)d_ws;
    float* sc = (float*)ws;                                  // [0]=dot [1]=fk0 [2]=fk1
    unsigned short* A0 = (unsigned short*)(ws + 256);        // X_trans bf16 [4096,512]
    unsigned short* A1 = A0 + (size_t)B_ROWS * D_K;          // Y_tgt  bf16
    unsigned short* B0 = A1 + (size_t)B_ROWS * D_K;          // Z_tgt  bf16 [32768,512]
    unsigned short* B1 = B0 + (size_t)N_COLS * D_K;          // Z_trans bf16
    uint2* P0 = (uint2*)(B1 + (size_t)N_COLS * D_K);         // [4096][256][2] uint2
    uint2* P1 = P0 + (size_t)B_ROWS * NCHUNK * 2;

    zero_scalars<<<1, 64, 0, stream>>>(sc);

    dim3 pgrid(2048, 4);
    prep_kernel<<<pgrid, 256, 0, stream>>>(
        (const float4*)X_trans, (const float4*)Y_tgt,
        (const float4*)Z_tgt, (const float4*)Z_trans,
        (ushort4*)A0, (ushort4*)A1, (ushort4*)B0, (ushort4*)B1, sc + 0);

    dim3 ggrid(8192, 2);
    gemm_topk_kernel<<<ggrid, 256, 0, stream>>>(A0, A1, B0, B1, P0, P1);

    dim3 mgrid(B_ROWS / 4, 2);
    merge_topk_kernel<<<mgrid, 256, 0, stream>>>(
        (const unsigned int*)P0, (const unsigned int*)P1, sc);

    finalize_kernel<<<1, 64, 0, stream>>>(sc, (float*)d_out);
}

// Round 5
// 800.114 us; speedup vs baseline: 2.0880x; 2.0880x over previous
//
#include <hip/hip_runtime.h>
#include <hip/hip_bf16.h>
#include <float.h>
#include <cstdint>

// ---------------------------------------------------------------------------
// RCSLS: out = ( topk10sum(X_trans@Z_tgt^T)/10 + topk10sum(Y_tgt@Z_trans^T)/10
//               - 2*sum(X_trans*Y_tgt) ) / 4096
// B=4096, N=32768, d=512, k=10.  Inputs f32; GEMMs in bf16 MFMA.
// Top-k carried as sortable-u16 (monotone bf16 map) for packed 16-bit sorts.
// Per (row, 64-col half) we keep top-4 (superset argument: P(>=5 of row top-10
// in one 64-col window) ~ 7e-12 per window — exact in practice).
// Staging: __builtin_amdgcn_global_load_lds width=16 (round-3 proven; the
// round-4 register double-buffer spilled to scratch: 6.6 GB HBM traffic).
// ---------------------------------------------------------------------------

#define B_ROWS 4096
#define N_COLS 32768
#define D_K    512
#define BM     128
#define BN     128
#define BKT    64
#define NCHUNK (N_COLS / BN)   // 256
#define CSTRIDE 134            // u16 C-dump stride: dump AND scan conflict-free

typedef __bf16 bf16x8 __attribute__((ext_vector_type(8)));
typedef float  f32x4  __attribute__((ext_vector_type(4)));
typedef unsigned short u16x2 __attribute__((ext_vector_type(2)));

__device__ __forceinline__ unsigned short f2bf(float f) {
    unsigned int u = __float_as_uint(f);
    u += 0x7FFFu + ((u >> 16) & 1u);   // RNE
    return (unsigned short)(u >> 16);
}
// monotone map: f32 order == unsigned order of f2sort(f)
__device__ __forceinline__ unsigned short f2sort(float f) {
    unsigned int x = f2bf(f);
    return (unsigned short)(x ^ (0x8000u | ((x >> 15) * 0x7FFFu)));
}
__device__ __forceinline__ float sort2f(unsigned int y) {
    unsigned int x = (y & 0x8000u) ? (y ^ 0x8000u) : (~y & 0xFFFFu);
    return __uint_as_float(x << 16);
}

__device__ __forceinline__ void gload_lds16(const void* g, void* l) {
    __builtin_amdgcn_global_load_lds(
        (const __attribute__((address_space(1))) unsigned int*)(uintptr_t)g,
        (__attribute__((address_space(3))) unsigned int*)(uintptr_t)l,
        16, 0, 0);
}

// ---- zero the 3 scalar accumulators -----------------------------------------
__global__ void zero_scalars(float* sc) {
    if (threadIdx.x < 3) sc[threadIdx.x] = 0.0f;
}

// ---- fused f32->bf16 conversion (4 arrays) + dot(X,Y); grid.y selects ------
__global__ void prep_kernel(const float4* __restrict__ X,
                            const float4* __restrict__ Y,
                            const float4* __restrict__ Zt,
                            const float4* __restrict__ Ztr,
                            ushort4* __restrict__ A0, ushort4* __restrict__ A1,
                            ushort4* __restrict__ B0, ushort4* __restrict__ B1,
                            float* __restrict__ dotacc) {
    const int z = blockIdx.y;
    int i = blockIdx.x * 256 + threadIdx.x;
    const int stride = gridDim.x * 256;
    if (z == 0) {
        float s = 0.0f;
        for (; i < B_ROWS * D_K / 4; i += stride) {
            float4 x = X[i], y = Y[i];
            ushort4 u; u.x = f2bf(x.x); u.y = f2bf(x.y);
            u.z = f2bf(x.z); u.w = f2bf(x.w);
            A0[i] = u;
            s += x.x * y.x + x.y * y.y + x.z * y.z + x.w * y.w;
        }
        for (int o = 32; o > 0; o >>= 1) s += __shfl_down(s, o);
        __shared__ float wsum[4];
        int lane = threadIdx.x & 63, w = threadIdx.x >> 6;
        if (lane == 0) wsum[w] = s;
        __syncthreads();
        if (threadIdx.x == 0)
            atomicAdd(dotacc, wsum[0] + wsum[1] + wsum[2] + wsum[3]);
    } else {
        const float4* src = (z == 1) ? Y : (z == 2) ? Zt : Ztr;
        ushort4* dst = (z == 1) ? A1 : (z == 2) ? B0 : B1;
        int n4 = (z == 1) ? (B_ROWS * D_K / 4) : (N_COLS * D_K / 4);
        for (; i < n4; i += stride) {
            float4 f = src[i];
            ushort4 u; u.x = f2bf(f.x); u.y = f2bf(f.y);
            u.z = f2bf(f.z); u.w = f2bf(f.w);
            dst[i] = u;
        }
    }
}

// ---- bf16 GEMM + per-(row, 64-col-half) top-4 -------------------------------
// grid (8192, 2): y selects which GEMM. x is XCD-swizzled: xcd = b&7 owns
// chunks [xcd*32, xcd*32+32), iterating 16-chunk groups over row-blocks so the
// active B slice (2 MB) stays in that XCD's L2.
__global__ __launch_bounds__(256, 4)
void gemm_topk_kernel(const unsigned short* __restrict__ A0g,
                      const unsigned short* __restrict__ A1g,
                      const unsigned short* __restrict__ B0g,
                      const unsigned short* __restrict__ B1g,
                      uint2* __restrict__ P0, uint2* __restrict__ P1) {
    const unsigned short* A  = blockIdx.y ? A1g : A0g;
    const unsigned short* Bm = blockIdx.y ? B1g : B0g;
    uint2* P2 = blockIdx.y ? P1 : P0;

    __shared__ __align__(128) unsigned short smem[BM * CSTRIDE]; // 34304 B
    unsigned short* Alds = smem;             // 16 segs * 512 shorts (16 KB)
    unsigned short* Blds = smem + 16 * 512;  // 16 KB

    const int tid  = threadIdx.x;
    const int lane = tid & 63;
    const int w    = tid >> 6;
    const int wm   = w >> 1;
    const int wn   = w & 1;
    const int quad = lane >> 4;
    const int mrow = lane & 15;

    // XCD swizzle
    const int b      = blockIdx.x;
    const int xcd    = b & 7;
    const int ii     = b >> 3;            // 0..1023
    const int cw     = ii & 15;
    const int rowblk = (ii >> 4) & 31;
    const int cg     = ii >> 9;           // 0..1
    const int bn     = xcd * 32 + cg * 16 + cw;
    const int row0   = rowblk * BM;
    const int col0   = bn * BN;

    // per-lane global staging offsets (segment s = w*4+c):
    //   row-in-tile = (s>>1)*16 + (lane&15); col = (s&1)*32 + (lane>>4)*8
    const unsigned short* gA[4];
    const unsigned short* gB[4];
    #pragma unroll
    for (int c = 0; c < 4; ++c) {
        int s  = w * 4 + c;
        int r  = (s >> 1) * 16 + mrow;
        int kc = (s & 1) * 32 + quad * 8;
        gA[c] = A  + (size_t)(row0 + r) * D_K + kc;
        gB[c] = Bm + (size_t)(col0 + r) * D_K + kc;
    }

    f32x4 acc[4][4];
    #pragma unroll
    for (int mi = 0; mi < 4; ++mi)
        #pragma unroll
        for (int ni = 0; ni < 4; ++ni)
            acc[mi][ni] = (f32x4){0.f, 0.f, 0.f, 0.f};

    for (int kt = 0; kt < D_K; kt += BKT) {
        #pragma unroll
        for (int c = 0; c < 4; ++c) {
            int s = w * 4 + c;
            gload_lds16(gA[c] + kt, Alds + s * 512);
            gload_lds16(gB[c] + kt, Blds + s * 512);
        }
        __syncthreads();
        #pragma unroll
        for (int kk32 = 0; kk32 < 2; ++kk32) {
            bf16x8 af[4], bfr[4];
            #pragma unroll
            for (int mi = 0; mi < 4; ++mi)
                af[mi] = *(const bf16x8*)(Alds + ((wm * 4 + mi) * 2 + kk32) * 512 + lane * 8);
            #pragma unroll
            for (int ni = 0; ni < 4; ++ni)
                bfr[ni] = *(const bf16x8*)(Blds + ((wn * 4 + ni) * 2 + kk32) * 512 + lane * 8);
            #pragma unroll
            for (int mi = 0; mi < 4; ++mi)
                #pragma unroll
                for (int ni = 0; ni < 4; ++ni)
                    acc[mi][ni] = __builtin_amdgcn_mfma_f32_16x16x32_bf16(
                        af[mi], bfr[ni], acc[mi][ni], 0, 0, 0);
        }
        __syncthreads();
    }

    // ---- dump C as sortable u16, stride 134 (conflict-free) ----
    unsigned short* Cs = smem;
    #pragma unroll
    for (int mi = 0; mi < 4; ++mi) {
        int r = wm * 64 + mi * 16 + quad * 4;
        #pragma unroll
        for (int ni = 0; ni < 4; ++ni) {
            int cc = wn * 64 + ni * 16 + mrow;
            #pragma unroll
            for (int reg = 0; reg < 4; ++reg)
                Cs[(r + reg) * CSTRIDE + cc] = f2sort(acc[mi][ni][reg]);
        }
    }
    __syncthreads();

    // ---- per-half-row packed top-4: row = w*32+(lane>>1), half = lane&1 ----
    const int row  = w * 32 + (lane >> 1);
    const int half = lane & 1;
    const u16x2* rp = (const u16x2*)(Cs + row * CSTRIDE + half * 64);
    u16x2 t[4];
    #pragma unroll
    for (int i = 0; i < 4; ++i) t[i] = (u16x2){0, 0};
    #pragma unroll 8
    for (int j = 0; j < 32; ++j) {
        u16x2 v = rp[j];                       // (even col, odd col)
        #pragma unroll
        for (int i = 0; i < 4; ++i) {
            u16x2 hi = __builtin_elementwise_max(t[i], v);
            v = __builtin_elementwise_min(t[i], v);
            t[i] = hi;
        }
    }
    // bitonic first-stage: top-4 multiset of the 64 cols
    unsigned int m0 = max((unsigned int)t[0].x, (unsigned int)t[3].y);
    unsigned int m1 = max((unsigned int)t[1].x, (unsigned int)t[2].y);
    unsigned int m2 = max((unsigned int)t[2].x, (unsigned int)t[1].y);
    unsigned int m3 = max((unsigned int)t[3].x, (unsigned int)t[0].y);
    uint2 outv = make_uint2(m0 | (m1 << 16), m2 | (m3 << 16));
    P2[((size_t)(row0 + row) * NCHUNK + bn) * 2 + half] = outv;
}

// ---- per-row exact top-10 over 2048 u16 candidates; one wave per row --------
// grid (1024, 2): y selects which GEMM's P / accumulator.
__global__ __launch_bounds__(256, 4)
void merge_topk_kernel(const unsigned int* __restrict__ P0,
                       const unsigned int* __restrict__ P1,
                       float* __restrict__ sc) {
    const int g    = blockIdx.y;
    const int lane = threadIdx.x & 63;
    const int w    = threadIdx.x >> 6;
    const int row  = blockIdx.x * 4 + w;
    const unsigned int* Rp = (g ? P1 : P0) + (size_t)row * (NCHUNK * 4); // 1024 u32

    u16x2 t[10];
    #pragma unroll
    for (int i = 0; i < 10; ++i) t[i] = (u16x2){0, 0};
    #pragma unroll 4
    for (int it = 0; it < 16; ++it) {
        unsigned int raw = Rp[lane + 64 * it];
        u16x2 v = *(u16x2*)&raw;
        #pragma unroll
        for (int i = 0; i < 10; ++i) {
            u16x2 hi = __builtin_elementwise_max(t[i], v);
            v = __builtin_elementwise_min(t[i], v);
            t[i] = hi;
        }
    }
    // per-lane top-10 multiset, packed with (lane,slot) for unique extraction
    unsigned int wreg[10];
    #pragma unroll
    for (int i = 0; i < 10; ++i) {
        unsigned int mv = max((unsigned int)t[i].x,
                              (unsigned int)t[9 - i].y);
        wreg[i] = (mv << 16) | ((unsigned int)lane << 4) | (unsigned int)i;
    }
    float sum10 = 0.0f;
    #pragma unroll
    for (int iter = 0; iter < 10; ++iter) {
        unsigned int mx = wreg[0];
        #pragma unroll
        for (int s = 1; s < 10; ++s) mx = max(mx, wreg[s]);
        #pragma unroll
        for (int o = 32; o > 0; o >>= 1)
            mx = max(mx, (unsigned int)__shfl_xor((int)mx, o));
        sum10 += sort2f(mx >> 16);
        #pragma unroll
        for (int s = 0; s < 10; ++s)
            if (wreg[s] == mx) wreg[s] = 0u;
    }
    if (lane == 0) atomicAdd(sc + 1 + g, sum10);
}

// ---- final scalar -----------------------------------------------------------
__global__ void finalize_kernel(const float* __restrict__ sc,
                                float* __restrict__ out) {
    if (threadIdx.x == 0) {
        float f = (sc[1] * 0.1f + sc[2] * 0.1f - 2.0f * sc[0]) * (1.0f / 4096.0f);
        out[0] = f;
    }
}

extern "C" void kernel_launch(void* const* d_in, const int* in_sizes, int n_in,
                              void* d_out, int out_size, void* d_ws, size_t ws_size,
                              hipStream_t stream) {
    const float* X_trans = (const float*)d_in[1];
    const float* Y_tgt   = (const float*)d_in[2];
    const float* Z_trans = (const float*)d_in[4];
    const float* Z_tgt   = (const float*)d_in[5];

    char* ws = (char*)d_ws;
    float* sc = (float*)ws;                                  // [0]=dot [1]=fk0 [2]=fk1
    unsigned short* A0 = (unsigned short*)(ws + 256);        // X_trans bf16 [4096,512]
    unsigned short* A1 = A0 + (size_t)B_ROWS * D_K;          // Y_tgt  bf16
    unsigned short* B0 = A1 + (size_t)B_ROWS * D_K;          // Z_tgt  bf16 [32768,512]
    unsigned short* B1 = B0 + (size_t)N_COLS * D_K;          // Z_trans bf16
    uint2* P0 = (uint2*)(B1 + (size_t)N_COLS * D_K);         // [4096][256][2] uint2
    uint2* P1 = P0 + (size_t)B_ROWS * NCHUNK * 2;

    zero_scalars<<<1, 64, 0, stream>>>(sc);

    dim3 pgrid(2048, 4);
    prep_kernel<<<pgrid, 256, 0, stream>>>(
        (const float4*)X_trans, (const float4*)Y_tgt,
        (const float4*)Z_tgt, (const float4*)Z_trans,
        (ushort4*)A0, (ushort4*)A1, (ushort4*)B0, (ushort4*)B1, sc + 0);

    dim3 ggrid(8192, 2);
    gemm_topk_kernel<<<ggrid, 256, 0, stream>>>(A0, A1, B0, B1, P0, P1);

    dim3 mgrid(B_ROWS / 4, 2);
    merge_topk_kernel<<<mgrid, 256, 0, stream>>>(
        (const unsigned int*)P0, (const unsigned int*)P1, sc);

    finalize_kernel<<<1, 64, 0, stream>>>(sc, (float*)d_out);
}